// Round 13
// baseline (37.271 us; speedup 1.0000x reference)
//
#include <hip/hip_runtime.h>
#include <hip/hip_bf16.h>
#include <math.h>

#define Bsz 8
#define Nn  2048
#define Ff  256
#define KCAP 512
#define THR 60.0f

typedef short short8 __attribute__((ext_vector_type(8)));
typedef float f32x4  __attribute__((ext_vector_type(4)));
typedef unsigned short u16x4 __attribute__((ext_vector_type(4)));
typedef unsigned short u16x8 __attribute__((ext_vector_type(8)));
typedef unsigned int uint;

static __device__ __forceinline__ unsigned short f2bf(float v) {
    __hip_bfloat16 b = __float2bfloat16(v);
    return *reinterpret_cast<unsigned short*>(&b);
}
static __device__ __forceinline__ float bf2f(unsigned short u) {
    return __uint_as_float((uint)u << 16);
}
static __device__ __forceinline__ float fast_rcp(float x) {
    return __builtin_amdgcn_rcpf(x);
}

// ============ k1: heterogeneous ============
// blocks [0,256):    h = X@W^T + b -> h (B,N,F) bf16 ; s1 ; s2   (R12 k_h verbatim)
// blocks [256,2304): row-i shortlist -> compact global ent[i][*] + cnt[i] (atomics)
__global__ __launch_bounds__(512) void k1(const float* __restrict__ X,
                                          const float* __restrict__ Ageo,
                                          const float* __restrict__ Dm,
                                          const float* __restrict__ W,
                                          const float* __restrict__ Wb,
                                          const float* __restrict__ a1,
                                          const float* __restrict__ a2,
                                          const float* __restrict__ thr_p,
                                          unsigned short* __restrict__ h,
                                          float* __restrict__ s1,
                                          float* __restrict__ s2,
                                          uint4* __restrict__ ent,
                                          uint* __restrict__ cnt) {
    __shared__ char smem[45056];
    const int tid  = threadIdx.x;
    const int lane = tid & 63;
    const int w    = tid >> 6;

    if (blockIdx.x >= 256) {
        // ---------- shortlist path ----------
        const int i  = blockIdx.x - 256;
        const int j0 = tid * 4;
        const float c10 = 10.0f * thr_p[0];
        float4 a = *(const float4*)&Ageo[(size_t)i * Nn + j0];
        float4 d = *(const float4*)&Dm[(size_t)i * Nn + j0];
        float av[4] = {a.x, a.y, a.z, a.w};
        float dv[4] = {d.x, d.y, d.z, d.w};
        float mk[4], gg[4];
        float m = 0.0f;
#pragma unroll
        for (int c = 0; c < 4; c++) {
            float dd = (j0 + c == i) ? 1.0f : dv[c];
            float mkv = fast_rcp(1.0f + __expf(c10 - 10.0f * av[c]));
            float g   = mkv * fast_rcp(dd + 1e-5f);
            mk[c] = mkv;
            gg[c] = g;
            m = fmaxf(m, g);
        }
#pragma unroll
        for (int dd = 32; dd; dd >>= 1) m = fmaxf(m, __shfl_xor(m, dd));
        float* red = (float*)smem;
        if (lane == 0) red[w] = m;
        __syncthreads();
        float gmax = red[0];
#pragma unroll
        for (int k = 1; k < 8; k++) gmax = fmaxf(gmax, red[k]);
        const float cut = gmax - THR;
#pragma unroll
        for (int c = 0; c < 4; c++) {
            if (gg[c] > cut) {
                uint slot = atomicAdd(&cnt[i], 1u);
                if (slot < KCAP)
                    ent[((size_t)i << 9) + slot] =
                        make_uint4((uint)(j0 + c), __float_as_uint(mk[c]),
                                   __float_as_uint(gg[c] - gmax), 0u);
            }
        }
        return;
    }

    // ---------- h path (R12) ----------
    char* w_lds = smem;                                 // [256 o][64 f] bf16, byte ^= (o&7)<<4 ; reused as h-tile
    char* x_lds = smem + 32768;                         // [64 n][64 f] bf16, byte ^= (n&7)<<4
    float (*sred1)[4][16] = (float(*)[4][16])(smem + 40960);
    float (*sred2)[4][16] = (float(*)[4][16])(smem + 40960 + 2048);

    const int r0   = blockIdx.x * 64;
    const int b    = r0 >> 11;
    const int n0   = r0 & 2047;

    f32x4 acc[2][4];
#pragma unroll
    for (int mt = 0; mt < 2; mt++)
#pragma unroll
        for (int nt = 0; nt < 4; nt++) acc[mt][nt] = (f32x4)0.f;

    float4 wv[8], xv[2];
    auto gload = [&](int kc) {
        const int f0 = kc * 64;
#pragma unroll
        for (int p = 0; p < 8; p++) {
            int idx = tid + p * 512;
            int o = idx >> 4, fi = idx & 15;
            wv[p] = *(const float4*)&W[(size_t)o * Ff + f0 + fi * 4];
        }
#pragma unroll
        for (int p = 0; p < 2; p++) {
            int idx = tid + p * 512;
            int n = idx >> 4, fi = idx & 15;
            xv[p] = *(const float4*)&X[(size_t)(r0 + n) * Ff + f0 + fi * 4];
        }
    };
    auto swrite = [&]() {
#pragma unroll
        for (int p = 0; p < 8; p++) {
            int idx = tid + p * 512;
            int o = idx >> 4, fi = idx & 15;
            u16x4 pk = {f2bf(wv[p].x), f2bf(wv[p].y), f2bf(wv[p].z), f2bf(wv[p].w)};
            *(u16x4*)(w_lds + ((o * 128 + fi * 8) ^ ((o & 7) << 4))) = pk;
        }
#pragma unroll
        for (int p = 0; p < 2; p++) {
            int idx = tid + p * 512;
            int n = idx >> 4, fi = idx & 15;
            u16x4 pk = {f2bf(xv[p].x), f2bf(xv[p].y), f2bf(xv[p].z), f2bf(xv[p].w)};
            *(u16x4*)(x_lds + ((n * 128 + fi * 8) ^ ((n & 7) << 4))) = pk;
        }
    };

    gload(0);
    for (int kc = 0; kc < 4; kc++) {
        __syncthreads();
        swrite();
        __syncthreads();
        if (kc < 3) gload(kc + 1);
#pragma unroll
        for (int kt = 0; kt < 2; kt++) {
            short8 bfr[4];
#pragma unroll
            for (int nt = 0; nt < 4; nt++) {
                int n = nt * 16 + (lane & 15);
                bfr[nt] = *(const short8*)(x_lds + ((n * 128 + kt * 64 + (lane >> 4) * 16) ^ ((n & 7) << 4)));
            }
#pragma unroll
            for (int mt = 0; mt < 2; mt++) {
                int o = w * 32 + mt * 16 + (lane & 15);
                short8 afr = *(const short8*)(w_lds + ((o * 128 + kt * 64 + (lane >> 4) * 16) ^ ((o & 7) << 4)));
#pragma unroll
                for (int nt = 0; nt < 4; nt++)
                    acc[mt][nt] = __builtin_amdgcn_mfma_f32_16x16x32_bf16(afr, bfr[nt], acc[mt][nt], 0, 0, 0);
            }
        }
    }

    __syncthreads();    // reuse w_lds as h tile [64 n][256 o] bf16
    float s1p[4] = {0.f, 0.f, 0.f, 0.f};
    float s2p[4] = {0.f, 0.f, 0.f, 0.f};
#pragma unroll
    for (int mt = 0; mt < 2; mt++) {
#pragma unroll
        for (int reg = 0; reg < 4; reg++) {
            int o = w * 32 + mt * 16 + (lane >> 4) * 4 + reg;
            float wb = Wb[o], a1v = a1[o], a2v = a2[o];
#pragma unroll
            for (int nt = 0; nt < 4; nt++) {
                float hv = acc[mt][nt][reg] + wb;
                int nl = nt * 16 + (lane & 15);
                *(unsigned short*)(w_lds + nl * 512 + ((o * 2) ^ ((nl & 7) << 4))) = f2bf(hv);
                s1p[nt] += hv * a1v;
                s2p[nt] += hv * a2v;
            }
        }
    }
#pragma unroll
    for (int nt = 0; nt < 4; nt++) {
        s1p[nt] += __shfl_xor(s1p[nt], 16); s1p[nt] += __shfl_xor(s1p[nt], 32);
        s2p[nt] += __shfl_xor(s2p[nt], 16); s2p[nt] += __shfl_xor(s2p[nt], 32);
    }
    if (lane < 16) {
#pragma unroll
        for (int nt = 0; nt < 4; nt++) { sred1[w][nt][lane] = s1p[nt]; sred2[w][nt][lane] = s2p[nt]; }
    }
    __syncthreads();

#pragma unroll
    for (int p = 0; p < 4; p++) {
        int id = tid + p * 512;
        int nl = id >> 5;
        int c16 = (id & 31) * 16;
        u16x8 v = *(const u16x8*)(w_lds + nl * 512 + (c16 ^ ((nl & 7) << 4)));
        *(u16x8*)&h[((size_t)(b * Nn + n0 + nl)) * Ff + (id & 31) * 8] = v;
    }
    if (tid < 64) {
        int nt = tid >> 4, col = tid & 15;
        float v = 0.f;
#pragma unroll
        for (int k = 0; k < 8; k++) v += sred1[k][nt][col];
        s1[b * Nn + n0 + nt * 16 + col] = v;
    } else if (tid < 128) {
        int t2 = tid - 64;
        int nt = t2 >> 4, col = t2 & 15;
        float v = 0.f;
#pragma unroll
        for (int k = 0; k < 8; k++) v += sred2[k][nt][col];
        s2[b * Nn + n0 + nt * 16 + col] = v;
    }
}

// ============ k2: XCD-pinned sparse gather ============
// 1024 blocks x 512 thr; b = bid&7 (== XCD id -> h[b] 1MB stays in that XCD's L2).
// Block covers 16 rows; wave w handles rows i0 + w*2 + {0,1}; lane owns 4 f-cols.
__global__ __launch_bounds__(512) void k2(const unsigned short* __restrict__ h,
                                          const float* __restrict__ s1,
                                          const float* __restrict__ s2,
                                          const uint4* __restrict__ ent,
                                          const uint* __restrict__ cnt,
                                          const float* __restrict__ ab_p,
                                          float* __restrict__ out) {
    const int bid  = blockIdx.x;
    const int b    = bid & 7;
    const int i0   = (bid >> 3) * 16;
    const int lane = threadIdx.x & 63;
    const int w    = threadIdx.x >> 6;
    const float ab = ab_p[0];
    const float* s2b = s2 + b * Nn;
    const unsigned short* hb = h + (size_t)b * Nn * Ff;

#pragma unroll
    for (int rr = 0; rr < 2; rr++) {
        const int i = i0 + w * 2 + rr;
        const int C = min(cnt[i], (uint)KCAP);
        const float s1v = s1[b * Nn + i] + ab;
        const uint4* el = ent + ((size_t)i << 9);

        float4 acc = make_float4(0.f, 0.f, 0.f, 0.f);
        float psum = 0.f;

        uint4 e = el[0];
        float s2A = s2b[e.x];
        ushort4 hvA = *(const ushort4*)&hb[(size_t)e.x * Ff + lane * 4];

        for (int c = 0; c < C; c++) {
            int cn = (c + 1 < C) ? c + 1 : c;
            uint4 en = el[cn];
            float s2B = s2b[en.x];
            ushort4 hvB = *(const ushort4*)&hb[(size_t)en.x * Ff + lane * 4];
            float s = s1v + s2A;
            s = s > 0.f ? s : 0.1f * s;
            float p = __expf(s * __uint_as_float(e.y) + __uint_as_float(e.z));
            psum += p;
            acc.x += p * bf2f(hvA.x);
            acc.y += p * bf2f(hvA.y);
            acc.z += p * bf2f(hvA.z);
            acc.w += p * bf2f(hvA.w);
            e = en; s2A = s2B; hvA = hvB;
        }

        float inv = 1.0f / psum;
        *(float4*)&out[((size_t)(b * Nn + i)) * Ff + lane * 4] =
            make_float4(acc.x * inv, acc.y * inv, acc.z * inv, acc.w * inv);
    }
}

extern "C" void kernel_launch(void* const* d_in, const int* in_sizes, int n_in,
                              void* d_out, int out_size, void* d_ws, size_t ws_size,
                              hipStream_t stream) {
    const float* X    = (const float*)d_in[0];
    const float* Ageo = (const float*)d_in[1];
    const float* Dm   = (const float*)d_in[2];
    const float* Ww   = (const float*)d_in[3];
    const float* Wb   = (const float*)d_in[4];
    const float* a1   = (const float*)d_in[5];
    const float* a2   = (const float*)d_in[6];
    const float* ab   = (const float*)d_in[7];
    const float* thr  = (const float*)d_in[8];
    float* out = (float*)d_out;

    char* ws = (char*)d_ws;
    uint4* ent = (uint4*)ws;                                       // N*KCAP*16 = 16.8 MB
    uint*  cnt = (uint*)(ws + (size_t)Nn * KCAP * 16);             // N
    float* s1  = (float*)(cnt + Nn);                               // B*N
    float* s2  = s1 + (size_t)Bsz * Nn;                            // B*N
    unsigned short* h = (unsigned short*)(s2 + (size_t)Bsz * Nn);  // B*N*F bf16 = 8 MB

    hipMemsetAsync(cnt, 0, Nn * sizeof(uint), stream);
    k1<<<256 + Nn, 512, 0, stream>>>(X, Ageo, Dm, Ww, Wb, a1, a2, thr, h, s1, s2, ent, cnt);
    k2<<<1024, 512, 0, stream>>>(h, s1, s2, ent, cnt, ab, out);
}

// Round 14
// 26.920 us; speedup vs baseline: 1.3845x; 1.3845x over previous
//
#include <hip/hip_runtime.h>
#include <hip/hip_bf16.h>
#include <math.h>

#define Bsz 8
#define Nn  2048
#define Ff  256
#define KCAP 1024
#define THR 60.0f

typedef short short8 __attribute__((ext_vector_type(8)));
typedef float f32x4  __attribute__((ext_vector_type(4)));
typedef unsigned short u16x4 __attribute__((ext_vector_type(4)));
typedef unsigned short u16x8 __attribute__((ext_vector_type(8)));
typedef unsigned int uint;

static __device__ __forceinline__ unsigned short f2bf(float v) {
    __hip_bfloat16 b = __float2bfloat16(v);
    return *reinterpret_cast<unsigned short*>(&b);
}
static __device__ __forceinline__ float bf2f(unsigned short u) {
    return __uint_as_float((uint)u << 16);
}
static __device__ __forceinline__ float fast_rcp(float x) {
    return __builtin_amdgcn_rcpf(x);
}

// ============ k_h: h = X@W^T + b -> h (B,N,F) bf16 row-major ; s1 ; s2 ============
// (R12 verbatim) 256 blocks x 512 thr; reg-prefetch software pipeline.
__global__ __launch_bounds__(512) void k_h(const float* __restrict__ X,
                                           const float* __restrict__ W,
                                           const float* __restrict__ Wb,
                                           const float* __restrict__ a1,
                                           const float* __restrict__ a2,
                                           unsigned short* __restrict__ h,
                                           float* __restrict__ s1,
                                           float* __restrict__ s2) {
    __shared__ char smem[45056];
    char* w_lds = smem;                                 // [256 o][64 f] bf16, byte ^= (o&7)<<4 ; reused as h-tile
    char* x_lds = smem + 32768;                         // [64 n][64 f] bf16, byte ^= (n&7)<<4
    float (*sred1)[4][16] = (float(*)[4][16])(smem + 40960);
    float (*sred2)[4][16] = (float(*)[4][16])(smem + 40960 + 2048);

    const int tid  = threadIdx.x;
    const int lane = tid & 63;
    const int w    = tid >> 6;
    const int r0   = blockIdx.x * 64;
    const int b    = r0 >> 11;
    const int n0   = r0 & 2047;

    f32x4 acc[2][4];
#pragma unroll
    for (int mt = 0; mt < 2; mt++)
#pragma unroll
        for (int nt = 0; nt < 4; nt++) acc[mt][nt] = (f32x4)0.f;

    float4 wv[8], xv[2];
    auto gload = [&](int kc) {
        const int f0 = kc * 64;
#pragma unroll
        for (int p = 0; p < 8; p++) {
            int idx = tid + p * 512;
            int o = idx >> 4, fi = idx & 15;
            wv[p] = *(const float4*)&W[(size_t)o * Ff + f0 + fi * 4];
        }
#pragma unroll
        for (int p = 0; p < 2; p++) {
            int idx = tid + p * 512;
            int n = idx >> 4, fi = idx & 15;
            xv[p] = *(const float4*)&X[(size_t)(r0 + n) * Ff + f0 + fi * 4];
        }
    };
    auto swrite = [&]() {
#pragma unroll
        for (int p = 0; p < 8; p++) {
            int idx = tid + p * 512;
            int o = idx >> 4, fi = idx & 15;
            u16x4 pk = {f2bf(wv[p].x), f2bf(wv[p].y), f2bf(wv[p].z), f2bf(wv[p].w)};
            *(u16x4*)(w_lds + ((o * 128 + fi * 8) ^ ((o & 7) << 4))) = pk;
        }
#pragma unroll
        for (int p = 0; p < 2; p++) {
            int idx = tid + p * 512;
            int n = idx >> 4, fi = idx & 15;
            u16x4 pk = {f2bf(xv[p].x), f2bf(xv[p].y), f2bf(xv[p].z), f2bf(xv[p].w)};
            *(u16x4*)(x_lds + ((n * 128 + fi * 8) ^ ((n & 7) << 4))) = pk;
        }
    };

    gload(0);
    for (int kc = 0; kc < 4; kc++) {
        __syncthreads();
        swrite();
        __syncthreads();
        if (kc < 3) gload(kc + 1);
#pragma unroll
        for (int kt = 0; kt < 2; kt++) {
            short8 bfr[4];
#pragma unroll
            for (int nt = 0; nt < 4; nt++) {
                int n = nt * 16 + (lane & 15);
                bfr[nt] = *(const short8*)(x_lds + ((n * 128 + kt * 64 + (lane >> 4) * 16) ^ ((n & 7) << 4)));
            }
#pragma unroll
            for (int mt = 0; mt < 2; mt++) {
                int o = w * 32 + mt * 16 + (lane & 15);
                short8 afr = *(const short8*)(w_lds + ((o * 128 + kt * 64 + (lane >> 4) * 16) ^ ((o & 7) << 4)));
#pragma unroll
                for (int nt = 0; nt < 4; nt++)
                    acc[mt][nt] = __builtin_amdgcn_mfma_f32_16x16x32_bf16(afr, bfr[nt], acc[mt][nt], 0, 0, 0);
            }
        }
    }

    __syncthreads();    // reuse w_lds as h tile [64 n][256 o] bf16
    float s1p[4] = {0.f, 0.f, 0.f, 0.f};
    float s2p[4] = {0.f, 0.f, 0.f, 0.f};
#pragma unroll
    for (int mt = 0; mt < 2; mt++) {
#pragma unroll
        for (int reg = 0; reg < 4; reg++) {
            int o = w * 32 + mt * 16 + (lane >> 4) * 4 + reg;
            float wb = Wb[o], a1v = a1[o], a2v = a2[o];
#pragma unroll
            for (int nt = 0; nt < 4; nt++) {
                float hv = acc[mt][nt][reg] + wb;
                int nl = nt * 16 + (lane & 15);
                *(unsigned short*)(w_lds + nl * 512 + ((o * 2) ^ ((nl & 7) << 4))) = f2bf(hv);
                s1p[nt] += hv * a1v;
                s2p[nt] += hv * a2v;
            }
        }
    }
#pragma unroll
    for (int nt = 0; nt < 4; nt++) {
        s1p[nt] += __shfl_xor(s1p[nt], 16); s1p[nt] += __shfl_xor(s1p[nt], 32);
        s2p[nt] += __shfl_xor(s2p[nt], 16); s2p[nt] += __shfl_xor(s2p[nt], 32);
    }
    if (lane < 16) {
#pragma unroll
        for (int nt = 0; nt < 4; nt++) { sred1[w][nt][lane] = s1p[nt]; sred2[w][nt][lane] = s2p[nt]; }
    }
    __syncthreads();

#pragma unroll
    for (int p = 0; p < 4; p++) {
        int id = tid + p * 512;
        int nl = id >> 5;
        int c16 = (id & 31) * 16;
        u16x8 v = *(const u16x8*)(w_lds + nl * 512 + (c16 ^ ((nl & 7) << 4)));
        *(u16x8*)&h[((size_t)(b * Nn + n0 + nl)) * Ff + (id & 31) * 8] = v;
    }
    if (tid < 64) {
        int nt = tid >> 4, col = tid & 15;
        float v = 0.f;
#pragma unroll
        for (int k = 0; k < 8; k++) v += sred1[k][nt][col];
        s1[b * Nn + n0 + nt * 16 + col] = v;
    } else if (tid < 128) {
        int t2 = tid - 64;
        int nt = t2 >> 4, col = t2 & 15;
        float v = 0.f;
#pragma unroll
        for (int k = 0; k < 8; k++) v += sred2[k][nt][col];
        s2[b * Nn + n0 + nt * 16 + col] = v;
    }
}

// ============ k_attn: fused shortlist + sparse gather-softmax ============
// grid = N blocks x 256 thr (4 waves -> 8 blocks/CU); block = row i.
// phase 1: 8 j/thread -> shortlist {j, mk, g-gmax} in LDS.
// phase 2: wave w gathers batches b=w and b=w+4 interleaved (2 indep chains).
__global__ __launch_bounds__(256) void k_attn(const unsigned short* __restrict__ h,
                                              const float* __restrict__ s1,
                                              const float* __restrict__ s2,
                                              const float* __restrict__ Ageo,
                                              const float* __restrict__ Dm,
                                              const float* __restrict__ ab_p,
                                              const float* __restrict__ thr_p,
                                              float* __restrict__ out) {
    __shared__ uint  ejs[KCAP];
    __shared__ float emks[KCAP];
    __shared__ float edgs[KCAP];
    __shared__ float red[4];
    __shared__ uint  cptr;

    const int i    = blockIdx.x;
    const int tid  = threadIdx.x;
    const int lane = tid & 63;
    const int w    = tid >> 6;      // 0..3
    const float c10 = 10.0f * thr_p[0];

    // ---- phase 1: shortlist for row i (8 j per thread) ----
    if (tid == 0) cptr = 0;
    const int j0 = tid * 8;
    float4 a0 = *(const float4*)&Ageo[(size_t)i * Nn + j0];
    float4 a1v = *(const float4*)&Ageo[(size_t)i * Nn + j0 + 4];
    float4 d0 = *(const float4*)&Dm[(size_t)i * Nn + j0];
    float4 d1 = *(const float4*)&Dm[(size_t)i * Nn + j0 + 4];
    float av[8] = {a0.x, a0.y, a0.z, a0.w, a1v.x, a1v.y, a1v.z, a1v.w};
    float dv[8] = {d0.x, d0.y, d0.z, d0.w, d1.x, d1.y, d1.z, d1.w};
    float mk[8], gg[8];
    float m = 0.0f;
#pragma unroll
    for (int c = 0; c < 8; c++) {
        float dd = (j0 + c == i) ? 1.0f : dv[c];
        float mkv = fast_rcp(1.0f + __expf(c10 - 10.0f * av[c]));
        float g   = mkv * fast_rcp(dd + 1e-5f);
        mk[c] = mkv;
        gg[c] = g;
        m = fmaxf(m, g);
    }
#pragma unroll
    for (int dd = 32; dd; dd >>= 1) m = fmaxf(m, __shfl_xor(m, dd));
    if (lane == 0) red[w] = m;
    __syncthreads();
    float gmax = fmaxf(fmaxf(red[0], red[1]), fmaxf(red[2], red[3]));
    const float cut = gmax - THR;
#pragma unroll
    for (int c = 0; c < 8; c++) {
        if (gg[c] > cut) {
            uint slot = atomicAdd(&cptr, 1u);
            if (slot < KCAP) {
                ejs[slot]  = (uint)(j0 + c);
                emks[slot] = mk[c];
                edgs[slot] = gg[c] - gmax;
            }
        }
    }
    __syncthreads();
    const int C = min(cptr, (uint)KCAP);

    // ---- phase 2: wave w gathers batches b0 = w, b1 = w+4 (interleaved chains) ----
    const int b0 = w, b1 = w + 4;
    const float ab = ab_p[0];
    const float s1v0 = s1[b0 * Nn + i] + ab;
    const float s1v1 = s1[b1 * Nn + i] + ab;
    const float* s2b0 = s2 + b0 * Nn;
    const float* s2b1 = s2 + b1 * Nn;
    const unsigned short* h0 = h + (size_t)b0 * Nn * Ff;
    const unsigned short* h1 = h + (size_t)b1 * Nn * Ff;

    float4 acc0 = make_float4(0.f, 0.f, 0.f, 0.f);
    float4 acc1 = make_float4(0.f, 0.f, 0.f, 0.f);
    float ps0 = 0.f, ps1 = 0.f;

    uint  jA  = ejs[0];
    float mkA = emks[0];
    float dgA = edgs[0];
    float s2A0 = s2b0[jA], s2A1 = s2b1[jA];
    ushort4 hvA0 = *(const ushort4*)&h0[(size_t)jA * Ff + lane * 4];
    ushort4 hvA1 = *(const ushort4*)&h1[(size_t)jA * Ff + lane * 4];

    for (int c = 0; c < C; c++) {
        int cn = (c + 1 < C) ? c + 1 : c;
        uint  jB  = ejs[cn];
        float mkB = emks[cn];
        float dgB = edgs[cn];
        float s2B0 = s2b0[jB], s2B1 = s2b1[jB];
        ushort4 hvB0 = *(const ushort4*)&h0[(size_t)jB * Ff + lane * 4];
        ushort4 hvB1 = *(const ushort4*)&h1[(size_t)jB * Ff + lane * 4];

        float sa = s1v0 + s2A0;
        sa = sa > 0.f ? sa : 0.1f * sa;
        float p0 = __expf(sa * mkA + dgA);
        ps0 += p0;
        acc0.x += p0 * bf2f(hvA0.x);
        acc0.y += p0 * bf2f(hvA0.y);
        acc0.z += p0 * bf2f(hvA0.z);
        acc0.w += p0 * bf2f(hvA0.w);

        float sb = s1v1 + s2A1;
        sb = sb > 0.f ? sb : 0.1f * sb;
        float p1 = __expf(sb * mkA + dgA);
        ps1 += p1;
        acc1.x += p1 * bf2f(hvA1.x);
        acc1.y += p1 * bf2f(hvA1.y);
        acc1.z += p1 * bf2f(hvA1.z);
        acc1.w += p1 * bf2f(hvA1.w);

        jA = jB; mkA = mkB; dgA = dgB;
        s2A0 = s2B0; s2A1 = s2B1; hvA0 = hvB0; hvA1 = hvB1;
    }

    float inv0 = 1.0f / ps0;
    float inv1 = 1.0f / ps1;
    *(float4*)&out[((size_t)(b0 * Nn + i)) * Ff + lane * 4] =
        make_float4(acc0.x * inv0, acc0.y * inv0, acc0.z * inv0, acc0.w * inv0);
    *(float4*)&out[((size_t)(b1 * Nn + i)) * Ff + lane * 4] =
        make_float4(acc1.x * inv1, acc1.y * inv1, acc1.z * inv1, acc1.w * inv1);
}

extern "C" void kernel_launch(void* const* d_in, const int* in_sizes, int n_in,
                              void* d_out, int out_size, void* d_ws, size_t ws_size,
                              hipStream_t stream) {
    const float* X    = (const float*)d_in[0];
    const float* Ageo = (const float*)d_in[1];
    const float* Dm   = (const float*)d_in[2];
    const float* Ww   = (const float*)d_in[3];
    const float* Wb   = (const float*)d_in[4];
    const float* a1   = (const float*)d_in[5];
    const float* a2   = (const float*)d_in[6];
    const float* ab   = (const float*)d_in[7];
    const float* thr  = (const float*)d_in[8];
    float* out = (float*)d_out;

    char* ws = (char*)d_ws;
    float* s1 = (float*)ws;                                        // B*N
    float* s2 = s1 + (size_t)Bsz * Nn;                             // B*N
    unsigned short* h = (unsigned short*)(s2 + (size_t)Bsz * Nn);  // B*N*F bf16 = 8 MB

    k_h<<<256, 512, 0, stream>>>(X, Ww, Wb, a1, a2, h, s1, s2);
    k_attn<<<Nn, 256, 0, stream>>>(h, s1, s2, Ageo, Dm, ab, thr, out);
}